// Round 1
// baseline (692.341 us; speedup 1.0000x reference)
//
#include <hip/hip_runtime.h>
#include <math.h>

#define CIN 256
#define COUT 256
#define NB 8
#define HID 128
#define HW 4096
#define BATCH 64

// ---------------- K0: repack base_filters [n][c*9+d] -> fT[(c*9+d)*8+n] ----
__global__ __launch_bounds__(256) void repack_filters(
    const float* __restrict__ bf, float* __restrict__ fT) {
  int i = blockIdx.x * 256 + threadIdx.x;  // over 8*2304 = 18432
  if (i < 8 * 2304) {
    int n = i / 2304;
    int cd = i % 2304;
    fT[cd * 8 + n] = bf[i];
  }
}

// ---------------- K1: conv (x -> ypart) + pooling partials -----------------
// grid 256: bid = b*4 + chhalf*2 + rchunk. block 256.
// Each block: 128 channels, 32 output rows, all 8 filters, 64 cols.
// Thread: 8 filters x 8 cols (one row) = 64 fp32 accumulators.
// LDS x tile: 8 ch x 34 rows x 68 (stride-padded; col 0 & 65 are zero pad).
__global__ __launch_bounds__(256) void conv_pool_kernel(
    const float* __restrict__ x, const float* __restrict__ fT,
    float* __restrict__ ypart, float* __restrict__ poolpart) {
  __shared__ float xs[8 * 34 * 68];  // 73,984 B
  const int t = threadIdx.x;
  const int bid = blockIdx.x;
  const int b = bid >> 2;
  const int chhalf = (bid >> 1) & 1;
  const int rchunk = bid & 1;
  const int row0 = rchunk * 32;
  const int c0 = chhalf * 128;

  // zero LDS once: pad cols/rows stay zero forever (staging writes cols 1..64
  // of valid rows only)
  for (int i = t; i < 8 * 34 * 68; i += 256) xs[i] = 0.0f;
  __syncthreads();

  const int ch = t >> 5;   // staging channel 0..7
  const int part = t & 31; // staging lane within channel group
  const int r = t >> 3;    // conv output row 0..31
  const int cg = t & 7;    // conv col group (cols cg*8 .. cg*8+7)

  float acc[8][8];
#pragma unroll
  for (int n = 0; n < 8; ++n)
#pragma unroll
    for (int j = 0; j < 8; ++j) acc[n][j] = 0.0f;

  for (int chunk = 0; chunk < 16; ++chunk) {
    const int cbase = c0 + chunk * 8;
    // ---- stage 8 channels x 34 rows x 64 cols, accumulate pool partials ----
    float psum = 0.0f;
    const float* xsrc = x + ((size_t)(b * CIN + cbase + ch) * HW);
#pragma unroll
    for (int i = 0; i < 17; ++i) {
      int s = part + i * 32;  // 0..543
      int row = s >> 4;       // 0..33
      int seg = s & 15;       // float4 segment within row
      int grow = row0 + row - 1;
      if (grow >= 0 && grow < 64) {
        const float4 v = *(const float4*)(xsrc + grow * 64 + seg * 4);
        float* dst = &xs[(ch * 34 + row) * 68 + 1 + seg * 4];
        dst[0] = v.x; dst[1] = v.y; dst[2] = v.z; dst[3] = v.w;
        if (row >= 1 && row < 33) psum += (v.x + v.y) + (v.z + v.w);
      }
    }
    // reduce pool partial across the 32 lanes of this channel group
#pragma unroll
    for (int off = 16; off > 0; off >>= 1)
      psum += __shfl_down(psum, off, 32);
    if (part == 0)
      poolpart[(b * 2 + rchunk) * 256 + cbase + ch] = psum;
    __syncthreads();

    // ---- compute: 8 ch x 3x3 x 8 filters x 8 cols ----
#pragma unroll
    for (int cc = 0; cc < 8; ++cc) {
      const float* fb = fT + (size_t)(cbase + cc) * 72;  // wave-uniform -> s_load
      const float* xrow = &xs[(cc * 34 + r) * 68 + cg * 8];
#pragma unroll
      for (int dy = 0; dy < 3; ++dy) {
        const float* xr = xrow + dy * 68;  // 16B-aligned (stride 68 floats)
        float w[10];
        float4 a0 = *(const float4*)(xr);
        float4 a1 = *(const float4*)(xr + 4);
        float2 a2 = *(const float2*)(xr + 8);
        w[0] = a0.x; w[1] = a0.y; w[2] = a0.z; w[3] = a0.w;
        w[4] = a1.x; w[5] = a1.y; w[6] = a1.z; w[7] = a1.w;
        w[8] = a2.x; w[9] = a2.y;
#pragma unroll
        for (int dx = 0; dx < 3; ++dx) {
#pragma unroll
          for (int n = 0; n < 8; ++n) {
            const float fv = fb[(dy * 3 + dx) * 8 + n];  // uniform (SGPR)
#pragma unroll
            for (int j = 0; j < 8; ++j)
              acc[n][j] = fmaf(w[j + dx], fv, acc[n][j]);
          }
        }
      }
    }
    __syncthreads();
  }

  // write partial y for this channel-half: ypart[b][chhalf][n][row][col]
#pragma unroll
  for (int n = 0; n < 8; ++n) {
    float* yp = ypart +
        ((size_t)(((b * 2 + chhalf) * 8 + n) * 64 + row0 + r) * 64 + cg * 8);
    float4 v0 = {acc[n][0], acc[n][1], acc[n][2], acc[n][3]};
    float4 v1 = {acc[n][4], acc[n][5], acc[n][6], acc[n][7]};
    *(float4*)(yp) = v0;
    *(float4*)(yp + 4) = v1;
  }
}

// ---------------- K2: MLP + softmax -> mix [64][256][8] --------------------
__global__ __launch_bounds__(256) void mlp_kernel(
    const float* __restrict__ poolpart, const float* __restrict__ w1,
    const float* __restrict__ b1, const float* __restrict__ w2,
    const float* __restrict__ b2, float* __restrict__ mix) {
  __shared__ float pool_s[256];
  __shared__ float h_s[128];
  const int t = threadIdx.x;
  const int b = blockIdx.x;
  pool_s[t] = (poolpart[(b * 2 + 0) * 256 + t] +
               poolpart[(b * 2 + 1) * 256 + t]) * (1.0f / 4096.0f);
  __syncthreads();
  if (t < 128) {
    float a = b1[t];
    const float* wr = w1 + t * 256;
    for (int c = 0; c < 256; c += 4) {
      float4 wv = *(const float4*)(wr + c);
      a = fmaf(pool_s[c], wv.x, a);
      a = fmaf(pool_s[c + 1], wv.y, a);
      a = fmaf(pool_s[c + 2], wv.z, a);
      a = fmaf(pool_s[c + 3], wv.w, a);
    }
    h_s[t] = fmaxf(a, 0.0f);
  }
  __syncthreads();
  float m[8];
#pragma unroll
  for (int n = 0; n < 8; ++n) {
    float a = b2[t * 8 + n];
    const float* wr = w2 + (size_t)(t * 8 + n) * 128;
    for (int j = 0; j < 128; j += 4) {
      float4 wv = *(const float4*)(wr + j);
      a = fmaf(h_s[j], wv.x, a);
      a = fmaf(h_s[j + 1], wv.y, a);
      a = fmaf(h_s[j + 2], wv.z, a);
      a = fmaf(h_s[j + 3], wv.w, a);
    }
    m[n] = a;
  }
  float mx = m[0];
#pragma unroll
  for (int n = 1; n < 8; ++n) mx = fmaxf(mx, m[n]);
  float s = 0.0f;
#pragma unroll
  for (int n = 0; n < 8; ++n) {
    m[n] = __expf(m[n] - mx);
    s += m[n];
  }
  float inv = 1.0f / s;
#pragma unroll
  for (int n = 0; n < 8; ++n) mix[(size_t)(b * 256 + t) * 8 + n] = m[n] * inv;
}

// ---------------- K3: out[b][o][p] = sum_n mix[b][o][n] * y[b][n][p] -------
// grid 256: bid = b*4 + tile (1024 positions per tile). block 256.
__global__ __launch_bounds__(256) void mix_conv_kernel(
    const float* __restrict__ ypart, const float* __restrict__ mix,
    float* __restrict__ out) {
  __shared__ float ys[8 * 1024];    // 32 KB
  __shared__ float mix_s[2048];     // 8 KB
  const int t = threadIdx.x;
  const int b = blockIdx.x >> 2;
  const int tile = blockIdx.x & 3;
  const int p0 = tile * 1024;

  const float* y0 = ypart + (size_t)(b * 2 + 0) * 8 * HW + p0;
  const float* y1 = ypart + (size_t)(b * 2 + 1) * 8 * HW + p0;
  for (int i = t; i < 2048; i += 256) {  // 2048 float4 slots = 8 x 1024 floats
    int n = i >> 8;
    int pv = i & 255;
    float4 a = *(const float4*)(y0 + n * HW + pv * 4);
    float4 c = *(const float4*)(y1 + n * HW + pv * 4);
    float4 r = {a.x + c.x, a.y + c.y, a.z + c.z, a.w + c.w};
    *(float4*)&ys[n * 1024 + pv * 4] = r;
  }
  {
    const float4* ms = (const float4*)(mix + (size_t)b * 2048);
    float4* md = (float4*)mix_s;
    for (int i = t; i < 512; i += 256) md[i] = ms[i];
  }
  __syncthreads();

  float4 y4[8];
#pragma unroll
  for (int n = 0; n < 8; ++n) y4[n] = *(const float4*)&ys[n * 1024 + t * 4];

  float* op = out + (size_t)b * COUT * HW + p0 + t * 4;
  for (int o = 0; o < 256; ++o) {
    float4 ma = *(const float4*)&mix_s[o * 8];      // uniform -> broadcast
    float4 mb = *(const float4*)&mix_s[o * 8 + 4];
    float4 r;
    r.x = ma.x * y4[0].x; r.y = ma.x * y4[0].y;
    r.z = ma.x * y4[0].z; r.w = ma.x * y4[0].w;
    r.x = fmaf(ma.y, y4[1].x, r.x); r.y = fmaf(ma.y, y4[1].y, r.y);
    r.z = fmaf(ma.y, y4[1].z, r.z); r.w = fmaf(ma.y, y4[1].w, r.w);
    r.x = fmaf(ma.z, y4[2].x, r.x); r.y = fmaf(ma.z, y4[2].y, r.y);
    r.z = fmaf(ma.z, y4[2].z, r.z); r.w = fmaf(ma.z, y4[2].w, r.w);
    r.x = fmaf(ma.w, y4[3].x, r.x); r.y = fmaf(ma.w, y4[3].y, r.y);
    r.z = fmaf(ma.w, y4[3].z, r.z); r.w = fmaf(ma.w, y4[3].w, r.w);
    r.x = fmaf(mb.x, y4[4].x, r.x); r.y = fmaf(mb.x, y4[4].y, r.y);
    r.z = fmaf(mb.x, y4[4].z, r.z); r.w = fmaf(mb.x, y4[4].w, r.w);
    r.x = fmaf(mb.y, y4[5].x, r.x); r.y = fmaf(mb.y, y4[5].y, r.y);
    r.z = fmaf(mb.y, y4[5].z, r.z); r.w = fmaf(mb.y, y4[5].w, r.w);
    r.x = fmaf(mb.z, y4[6].x, r.x); r.y = fmaf(mb.z, y4[6].y, r.y);
    r.z = fmaf(mb.z, y4[6].z, r.z); r.w = fmaf(mb.z, y4[6].w, r.w);
    r.x = fmaf(mb.w, y4[7].x, r.x); r.y = fmaf(mb.w, y4[7].y, r.y);
    r.z = fmaf(mb.w, y4[7].z, r.z); r.w = fmaf(mb.w, y4[7].w, r.w);
    *(float4*)(op + (size_t)o * HW) = r;
  }
}

// ---------------- launch ---------------------------------------------------
extern "C" void kernel_launch(void* const* d_in, const int* in_sizes, int n_in,
                              void* d_out, int out_size, void* d_ws,
                              size_t ws_size, hipStream_t stream) {
  const float* x  = (const float*)d_in[0];
  const float* w1 = (const float*)d_in[1];
  const float* b1 = (const float*)d_in[2];
  const float* w2 = (const float*)d_in[3];
  const float* b2 = (const float*)d_in[4];
  const float* bf = (const float*)d_in[5];
  float* out = (float*)d_out;

  char* ws = (char*)d_ws;
  float* ypart    = (float*)(ws);                        // 64*2*8*4096*4 = 16,777,216 B
  float* poolpart = (float*)(ws + 16777216);             // 64*2*256*4   =    131,072 B
  float* mixw     = (float*)(ws + 16777216 + 131072);    // 64*256*8*4   =  2,097,152 B
  float* fT       = (float*)(ws + 16777216 + 131072 + 2097152);  // 73,728 B

  repack_filters<<<72, 256, 0, stream>>>(bf, fT);
  conv_pool_kernel<<<256, 256, 0, stream>>>(x, fT, ypart, poolpart);
  mlp_kernel<<<64, 256, 0, stream>>>(poolpart, w1, b1, w2, b2, mixw);
  mix_conv_kernel<<<256, 256, 0, stream>>>(ypart, mixw, out);
}

// Round 2
// 581.146 us; speedup vs baseline: 1.1913x; 1.1913x over previous
//
#include <hip/hip_runtime.h>
#include <math.h>

#define CIN 256
#define COUT 256
#define NB 8
#define HID 128
#define HW 4096
#define BATCH 64

#define TROWS 18    // 16 output rows + 2 halo
#define XSTR 68     // row stride in LDS (1 left pad + 64 + 3 right pad)

// ---------------- K0: repack base_filters [n][c*9+d] -> fT[(c*9+d)*8+n] ----
__global__ __launch_bounds__(256) void repack_filters(
    const float* __restrict__ bf, float* __restrict__ fT) {
  int i = blockIdx.x * 256 + threadIdx.x;  // over 8*2304 = 18432
  if (i < 8 * 2304) {
    int n = i / 2304;
    int cd = i % 2304;
    fT[cd * 8 + n] = bf[i];
  }
}

// ---------------- K1: conv (x -> ypart) + pooling partials -----------------
// grid 1024: bid = b*16 + g*4 + rc. block 256, 4 blocks/CU (LDS 39KB, VGPR<=128)
// Block: 64 channels (group g), 16 output rows (chunk rc), 8 filters, 64 cols.
// Thread: 8 filters x 4 cols (one row) = 32 fp32 accumulators.
__global__ __launch_bounds__(256, 4) void conv_pool_kernel(
    const float* __restrict__ x, const float* __restrict__ fT,
    float* __restrict__ ypart, float* __restrict__ poolpart) {
  __shared__ float xs[8 * TROWS * XSTR];  // 39,168 B
  const int t = threadIdx.x;
  const int bid = blockIdx.x;
  const int b = bid >> 4;
  const int g = (bid >> 2) & 3;
  const int rc = bid & 3;
  const int row0 = rc * 16;
  const int c0 = g * 64;

  // zero once: pad cols + out-of-image halo rows stay zero for all chunks
  for (int i = t; i < 8 * TROWS * XSTR; i += 256) xs[i] = 0.0f;
  __syncthreads();

  const int ch = t >> 5;   // staging channel 0..7
  const int part = t & 31; // staging lane within channel group
  const int r = t >> 4;    // conv output row 0..15
  const int cg = t & 15;   // conv col group (cols cg*4 .. cg*4+3)

  float acc[8][4];
#pragma unroll
  for (int n = 0; n < 8; ++n)
#pragma unroll
    for (int j = 0; j < 4; ++j) acc[n][j] = 0.0f;

#pragma unroll 1
  for (int chunk = 0; chunk < 8; ++chunk) {
    const int cbase = c0 + chunk * 8;
    // ---- stage 8 ch x 18 rows x 64 cols, accumulate pool partials ----
    float psum = 0.0f;
    const float* xsrc = x + ((size_t)(b * CIN + cbase + ch) * HW);
#pragma unroll
    for (int i = 0; i < 9; ++i) {
      int s = part + i * 32;  // 0..287
      int row = s >> 4;       // 0..17
      int seg = s & 15;       // float4 segment within row
      int grow = row0 + row - 1;
      if (grow >= 0 && grow < 64) {
        const float4 v = *(const float4*)(xsrc + grow * 64 + seg * 4);
        float* dst = &xs[(ch * TROWS + row) * XSTR + 1 + seg * 4];
        dst[0] = v.x; dst[1] = v.y; dst[2] = v.z; dst[3] = v.w;
        if (row >= 1 && row <= 16) psum += (v.x + v.y) + (v.z + v.w);
      }
    }
#pragma unroll
    for (int off = 16; off > 0; off >>= 1)
      psum += __shfl_down(psum, off, 32);
    if (part == 0)
      poolpart[(b * 4 + rc) * 256 + cbase + ch] = psum;
    __syncthreads();

    // ---- compute: 8 ch x 3x3 x 8 filters x 4 cols ----
#pragma unroll
    for (int cc = 0; cc < 8; ++cc) {
      const float* fb = fT + (size_t)(cbase + cc) * 72;  // wave-uniform -> s_load
      const float* xrow = &xs[(cc * TROWS + r) * XSTR + cg * 4];
#pragma unroll
      for (int dy = 0; dy < 3; ++dy) {
        const float* xr = xrow + dy * XSTR;  // 16B aligned
        float4 a0 = *(const float4*)(xr);
        float2 a1 = *(const float2*)(xr + 4);
        float w[6];
        w[0] = a0.x; w[1] = a0.y; w[2] = a0.z; w[3] = a0.w;
        w[4] = a1.x; w[5] = a1.y;
#pragma unroll
        for (int dx = 0; dx < 3; ++dx) {
#pragma unroll
          for (int n = 0; n < 8; ++n) {
            const float fv = fb[(dy * 3 + dx) * 8 + n];  // uniform (SGPR)
#pragma unroll
            for (int j = 0; j < 4; ++j)
              acc[n][j] = fmaf(w[j + dx], fv, acc[n][j]);
          }
        }
      }
    }
    __syncthreads();
  }

  // write partial y for this channel-group: ypart[b][g][n][row][col]
#pragma unroll
  for (int n = 0; n < 8; ++n) {
    float* yp = ypart +
        ((size_t)(((b * 4 + g) * 8 + n) * 64 + row0 + r) * 64 + cg * 4);
    float4 v0 = {acc[n][0], acc[n][1], acc[n][2], acc[n][3]};
    *(float4*)(yp) = v0;
  }
}

// ---------------- K2: MLP + softmax -> mix [64][256][8] --------------------
__global__ __launch_bounds__(256) void mlp_kernel(
    const float* __restrict__ poolpart, const float* __restrict__ w1,
    const float* __restrict__ b1, const float* __restrict__ w2,
    const float* __restrict__ b2, float* __restrict__ mix) {
  __shared__ float pool_s[256];
  __shared__ float h_s[128];
  const int t = threadIdx.x;
  const int b = blockIdx.x;
  pool_s[t] = (poolpart[(b * 4 + 0) * 256 + t] +
               poolpart[(b * 4 + 1) * 256 + t] +
               poolpart[(b * 4 + 2) * 256 + t] +
               poolpart[(b * 4 + 3) * 256 + t]) * (1.0f / 4096.0f);
  __syncthreads();
  if (t < 128) {
    float a = b1[t];
    const float* wr = w1 + t * 256;
    for (int c = 0; c < 256; c += 4) {
      float4 wv = *(const float4*)(wr + c);
      a = fmaf(pool_s[c], wv.x, a);
      a = fmaf(pool_s[c + 1], wv.y, a);
      a = fmaf(pool_s[c + 2], wv.z, a);
      a = fmaf(pool_s[c + 3], wv.w, a);
    }
    h_s[t] = fmaxf(a, 0.0f);
  }
  __syncthreads();
  float m[8];
#pragma unroll
  for (int n = 0; n < 8; ++n) {
    float a = b2[t * 8 + n];
    const float* wr = w2 + (size_t)(t * 8 + n) * 128;
    for (int j = 0; j < 128; j += 4) {
      float4 wv = *(const float4*)(wr + j);
      a = fmaf(h_s[j], wv.x, a);
      a = fmaf(h_s[j + 1], wv.y, a);
      a = fmaf(h_s[j + 2], wv.z, a);
      a = fmaf(h_s[j + 3], wv.w, a);
    }
    m[n] = a;
  }
  float mx = m[0];
#pragma unroll
  for (int n = 1; n < 8; ++n) mx = fmaxf(mx, m[n]);
  float s = 0.0f;
#pragma unroll
  for (int n = 0; n < 8; ++n) {
    m[n] = __expf(m[n] - mx);
    s += m[n];
  }
  float inv = 1.0f / s;
#pragma unroll
  for (int n = 0; n < 8; ++n) mix[(size_t)(b * 256 + t) * 8 + n] = m[n] * inv;
}

// ---------------- K3: out[b][o][p] = sum_n mix[b][o][n] * y[b][n][p] -------
// grid 256: bid = b*4 + tile (1024 positions per tile). block 256.
__global__ __launch_bounds__(256) void mix_conv_kernel(
    const float* __restrict__ ypart, const float* __restrict__ mix,
    float* __restrict__ out) {
  __shared__ float ys[8 * 1024];    // 32 KB
  __shared__ float mix_s[2048];     // 8 KB
  const int t = threadIdx.x;
  const int b = blockIdx.x >> 2;
  const int tile = blockIdx.x & 3;
  const int p0 = tile * 1024;

  const float* yb = ypart + (size_t)b * 4 * 8 * HW + p0;
  for (int i = t; i < 2048; i += 256) {  // 2048 float4 slots = 8 x 1024 floats
    int n = i >> 8;
    int pv = i & 255;
    const float* y0 = yb + n * HW + pv * 4;
    float4 a = *(const float4*)(y0);
    float4 c = *(const float4*)(y0 + 8 * HW);
    float4 d = *(const float4*)(y0 + 16 * HW);
    float4 e = *(const float4*)(y0 + 24 * HW);
    float4 rr = {a.x + c.x + d.x + e.x, a.y + c.y + d.y + e.y,
                 a.z + c.z + d.z + e.z, a.w + c.w + d.w + e.w};
    *(float4*)&ys[n * 1024 + pv * 4] = rr;
  }
  {
    const float4* ms = (const float4*)(mix + (size_t)b * 2048);
    float4* md = (float4*)mix_s;
    for (int i = t; i < 512; i += 256) md[i] = ms[i];
  }
  __syncthreads();

  float4 y4[8];
#pragma unroll
  for (int n = 0; n < 8; ++n) y4[n] = *(const float4*)&ys[n * 1024 + t * 4];

  float* op = out + (size_t)b * COUT * HW + p0 + t * 4;
  for (int o = 0; o < 256; ++o) {
    float4 ma = *(const float4*)&mix_s[o * 8];      // uniform -> broadcast
    float4 mb = *(const float4*)&mix_s[o * 8 + 4];
    float4 r;
    r.x = ma.x * y4[0].x; r.y = ma.x * y4[0].y;
    r.z = ma.x * y4[0].z; r.w = ma.x * y4[0].w;
    r.x = fmaf(ma.y, y4[1].x, r.x); r.y = fmaf(ma.y, y4[1].y, r.y);
    r.z = fmaf(ma.y, y4[1].z, r.z); r.w = fmaf(ma.y, y4[1].w, r.w);
    r.x = fmaf(ma.z, y4[2].x, r.x); r.y = fmaf(ma.z, y4[2].y, r.y);
    r.z = fmaf(ma.z, y4[2].z, r.z); r.w = fmaf(ma.z, y4[2].w, r.w);
    r.x = fmaf(ma.w, y4[3].x, r.x); r.y = fmaf(ma.w, y4[3].y, r.y);
    r.z = fmaf(ma.w, y4[3].z, r.z); r.w = fmaf(ma.w, y4[3].w, r.w);
    r.x = fmaf(mb.x, y4[4].x, r.x); r.y = fmaf(mb.x, y4[4].y, r.y);
    r.z = fmaf(mb.x, y4[4].z, r.z); r.w = fmaf(mb.x, y4[4].w, r.w);
    r.x = fmaf(mb.y, y4[5].x, r.x); r.y = fmaf(mb.y, y4[5].y, r.y);
    r.z = fmaf(mb.y, y4[5].z, r.z); r.w = fmaf(mb.y, y4[5].w, r.w);
    r.x = fmaf(mb.z, y4[6].x, r.x); r.y = fmaf(mb.z, y4[6].y, r.y);
    r.z = fmaf(mb.z, y4[6].z, r.z); r.w = fmaf(mb.z, y4[6].w, r.w);
    r.x = fmaf(mb.w, y4[7].x, r.x); r.y = fmaf(mb.w, y4[7].y, r.y);
    r.z = fmaf(mb.w, y4[7].z, r.z); r.w = fmaf(mb.w, y4[7].w, r.w);
    *(float4*)(op + (size_t)o * HW) = r;
  }
}

// ---------------- launch ---------------------------------------------------
extern "C" void kernel_launch(void* const* d_in, const int* in_sizes, int n_in,
                              void* d_out, int out_size, void* d_ws,
                              size_t ws_size, hipStream_t stream) {
  const float* x  = (const float*)d_in[0];
  const float* w1 = (const float*)d_in[1];
  const float* b1 = (const float*)d_in[2];
  const float* w2 = (const float*)d_in[3];
  const float* b2 = (const float*)d_in[4];
  const float* bf = (const float*)d_in[5];
  float* out = (float*)d_out;

  char* ws = (char*)d_ws;
  float* ypart    = (float*)(ws);                     // 64*4*8*4096*4 = 33,554,432 B
  float* poolpart = (float*)(ws + 33554432);          // 64*4*256*4   =    262,144 B
  float* mixw     = (float*)(ws + 33554432 + 262144); // 64*256*8*4   =  2,097,152 B
  float* fT       = (float*)(ws + 33554432 + 262144 + 2097152);  // 73,728 B

  repack_filters<<<72, 256, 0, stream>>>(bf, fT);
  conv_pool_kernel<<<1024, 256, 0, stream>>>(x, fT, ypart, poolpart);
  mlp_kernel<<<64, 256, 0, stream>>>(poolpart, w1, b1, w2, b2, mixw);
  mix_conv_kernel<<<256, 256, 0, stream>>>(ypart, mixw, out);
}